// Round 12
// baseline (130.292 us; speedup 1.0000x reference)
//
#include <hip/hip_runtime.h>
#include <hip/hip_bf16.h>

#define B_  8
#define T_  1024
#define DI_ 256
#define C_  1024
#define O_  1024
#define KW  9
#define BT_ 8192
#define EPSF 1e-12f

typedef unsigned short u16;
typedef u16   ushort8 __attribute__((ext_vector_type(8)));
typedef u16   ushort4v __attribute__((ext_vector_type(4)));
typedef __bf16 bf16x8 __attribute__((ext_vector_type(8)));
typedef float  f32x4  __attribute__((ext_vector_type(4)));

#define GLOAD_LDS16(g, l) __builtin_amdgcn_global_load_lds( \
    (const __attribute__((address_space(1))) void*)(g),      \
    (__attribute__((address_space(3))) void*)(l), 16, 0, 0)

__device__ __forceinline__ float bf2f(u16 u) {
    union { unsigned int i; float f; } z; z.i = ((unsigned int)u) << 16; return z.f;
}
__device__ __forceinline__ u16 f2bf(float f) {
    union { float f; unsigned int i; } z; z.f = f;
    unsigned int i = z.i;
    i += 0x7FFFu + ((i >> 16) & 1u);   // RNE
    return (u16)(i >> 16);
}
__device__ __forceinline__ float mishf(float v) {
    float u = __expf(v);
    float w = 1.f + u;
    return v * (1.f - 2.f / (w * w + 1.f));
}

// ================= mega prep kernel =========================================
// [0,2048) cvt xb | [2048,2304) cvt w1 | [2304,2312) dnorm
// [2312,2824) pw fused: ssq partials + pwb=f2bf(p_w*g)  (single p_w read)
// [2824,2832) pb2[b][i] = sum_o w2[i][o]*p_b[b][o]
#define PB_XB 2048
#define PB_W1 2304
#define PB_DN 2312
#define PB_PW 2824
#define PB_TOT 2832

__global__ __launch_bounds__(256)
void prep_k(const float* __restrict__ x,   u16* __restrict__ xb,
            const float* __restrict__ w1w, u16* __restrict__ w1b16,
            const float* __restrict__ d_w, const float* __restrict__ d_g,
            float* __restrict__ dwf,
            const float* __restrict__ p_w, const float* __restrict__ p_g,
            u16* __restrict__ pwb, float* __restrict__ part,
            const float* __restrict__ w2w, const float* __restrict__ p_b,
            float* __restrict__ pb2)
{
    const int bid = blockIdx.x;
    const int tid = threadIdx.x;

    if (bid < PB_W1) {
        // ---- f32 -> bf16 converts ----
        const float* in;
        u16* out;
        int i;
        if (bid < PB_XB) { in = x;   out = xb;    i = bid * 256 + tid; }
        else             { in = w1w; out = w1b16; i = (bid - PB_XB) * 256 + tid; }
        float4 v = ((const float4*)in)[i];
        ushort4v o;
        o.x = f2bf(v.x); o.y = f2bf(v.y); o.z = f2bf(v.z); o.w = f2bf(v.w);
        ((ushort4v*)out)[i] = o;
    } else if (bid < PB_DN) {
        // ---- depthwise weight norm ----
        __shared__ float red[KW][256];
        __shared__ float nrm[KW];
        const int b = bid - PB_W1;
        float s[KW];
#pragma unroll
        for (int k = 0; k < KW; k++) s[k] = 0.f;
        for (int c = tid; c < C_; c += 256) {
#pragma unroll
            for (int k = 0; k < KW; k++) {
                float v = d_w[((size_t)b * C_ + c) * KW + k];
                s[k] += v * v;
            }
        }
#pragma unroll
        for (int k = 0; k < KW; k++) red[k][tid] = s[k];
        __syncthreads();
        if (tid < KW) {
            float t = 0.f;
            for (int i = 0; i < 256; i++) t += red[tid][i];
            nrm[tid] = fmaxf(sqrtf(t), EPSF);
        }
        __syncthreads();
        for (int c = tid; c < C_; c += 256) {
            float g = d_g[(size_t)b * C_ + c];
#pragma unroll
            for (int k = 0; k < KW; k++)
                dwf[((size_t)b * C_ + c) * KW + k] =
                    d_w[((size_t)b * C_ + c) * KW + k] / nrm[k] * g;
        }
    } else if (bid < PB_PW) {
        // ---- fused: part[b][cch][o] = ssq over 64 c;  pwb = bf16(p_w * g[c])
        const int idx = bid - PB_DN;
        const int b   = idx >> 6;
        const int rem = idx & 63;
        const int cch = rem >> 2;            // 0..15 (64 rows each)
        const int o   = (rem & 3) * 256 + tid;
        float ssq = 0.f;
#pragma unroll 8
        for (int r = 0; r < 64; r++) {
            const size_t row = (size_t)b * C_ + cch * 64 + r;
            float v = p_w[row * O_ + o];
            ssq += v * v;
            pwb[row * O_ + o] = f2bf(v * p_g[row]);
        }
        part[((size_t)b * 16 + cch) * O_ + o] = ssq;
    } else {
        // ---- pb2[b][i] = sum_o w2[i][o] * p_b[b][o]
        __shared__ float pbs[O_];
        const int b = bid - PB_PW;
        for (int j = tid; j < O_; j += 256) pbs[j] = p_b[(size_t)b * O_ + j];
        __syncthreads();
        const int i = tid;
        float s = 0.f;
        for (int o = 0; o < O_; o += 4) {
            float4 w = *(const float4*)&w2w[(size_t)i * O_ + o];
            s += w.x * pbs[o] + w.y * pbs[o + 1] + w.z * pbs[o + 2] + w.w * pbs[o + 3];
        }
        pb2[b * DI_ + i] = s;
    }
}

// ============ w2s_k: w2s[b][i][o] = bf16(w2[i][o] * inv_np[b][o]) ===========
__global__ __launch_bounds__(256)
void w2s_k(const float* __restrict__ w2w, const float* __restrict__ part,
           u16* __restrict__ w2s)
{
    const int bid = blockIdx.x;           // 128 blocks: b*16 + ich*4 + och
    const int tid = threadIdx.x;
    const int b   = bid >> 4;
    const int ich = (bid >> 2) & 3;       // 64 i-rows
    const int o   = (bid & 3) * 256 + tid;
    float s = 0.f;
#pragma unroll
    for (int ch = 0; ch < 16; ch++)
        s += part[((size_t)b * 16 + ch) * O_ + o];
    const float inv = 1.f / fmaxf(sqrtf(s), EPSF);
#pragma unroll 8
    for (int r = 0; r < 64; r++) {
        const int i = ich * 64 + r;
        w2s[((size_t)b * DI_ + i) * O_ + o] = f2bf(w2w[(size_t)i * O_ + o] * inv);
    }
}

// ---------------- depthwise conv along t + transpose write -------------------
__global__ __launch_bounds__(256)
void dwconv_k(const u16* __restrict__ h, const float* __restrict__ dwf,
              const float* __restrict__ d_b, u16* __restrict__ y1gT)
{
    __shared__ u16 hs[64][74];
    const int b  = blockIdx.z;
    const int c0 = blockIdx.y * 64, t0 = blockIdx.x * 64;
    const int tid = threadIdx.x;
    for (int idx = tid; idx < 64 * 72; idx += 256) {
        int cc = idx / 72, tt = idx % 72;
        int t = t0 + tt - 4;
        u16 v = 0;
        if (t >= 0 && t < T_) v = h[(size_t)(c0 + cc) * BT_ + b * T_ + t];
        hs[cc][tt] = v;
    }
    __syncthreads();
    const int cc = tid & 63;
    const int c  = c0 + cc;
    float w[KW];
#pragma unroll
    for (int k = 0; k < KW; k++) w[k] = dwf[((size_t)b * C_ + c) * KW + k];
    const float bb = d_b[(size_t)b * C_ + c];
    for (int tt = tid >> 6; tt < 64; tt += 4) {
        float s = bb;
#pragma unroll
        for (int k = 0; k < KW; k++) s += bf2f(hs[cc][tt + k]) * w[k];
        y1gT[((size_t)b * T_ + t0 + tt) * C_ + c] = f2bf(s);
    }
}

// ===== big GEMM body: 512 thr, BM=128 x BN=256, BK=64, 3-buf counted vmcnt ==
// EPI 0: D(bf16) = mish(v + bias[row]);  EPI 3: D(bf16) = v (no bias)
template<int EPI>
__device__ __forceinline__ void bgemm_body(
    const u16* __restrict__ A, const u16* __restrict__ Bt,
    u16* __restrict__ Db, const float* __restrict__ bias,
    int N, int Kd)
{
    __shared__ u16 As[3 * 128 * 64];   // 48 KB
    __shared__ u16 Bs[3 * 256 * 64];   // 96 KB

    const int gx = gridDim.x;
    const unsigned nwg = (unsigned)gx * gridDim.y;
    unsigned lin = blockIdx.y * gx + blockIdx.x;
    lin = (lin & 7u) * (nwg >> 3) + (lin >> 3);
    const int m0 = (int)(lin / gx) * 128;
    const int n0 = (int)(lin % gx) * 256;

    const int tid  = threadIdx.x;
    const int lane = tid & 63, wave = tid >> 6;
    const int wm = (wave >> 2) * 64, wn = (wave & 3) * 64;
    const int lr = lane & 15;
    const int srow8 = tid >> 3;
    const int scolE = ((tid & 7) ^ ((tid >> 3) & 7)) * 8;

    f32x4 acc[4][4];
#pragma unroll
    for (int i = 0; i < 4; i++)
#pragma unroll
        for (int j = 0; j < 4; j++) acc[i][j] = (f32x4){0.f, 0.f, 0.f, 0.f};

    auto STAGE = [&](int buf, int kt) {
        const int k0 = kt << 6;
#pragma unroll
        for (int i = 0; i < 2; i++)
            GLOAD_LDS16(&A[(size_t)(m0 + i * 64 + srow8) * Kd + k0 + scolE],
                        &As[buf * 8192 + (i * 64 + wave * 8) * 64]);
#pragma unroll
        for (int i = 0; i < 4; i++)
            GLOAD_LDS16(&Bt[(size_t)(n0 + i * 64 + srow8) * Kd + k0 + scolE],
                        &Bs[buf * 16384 + (i * 64 + wave * 8) * 64]);
    };

    const int NT = Kd >> 6;
    STAGE(0, 0);
    STAGE(1, 1);
    int rb = 0, sb = 2;
    for (int kt = 0; kt < NT; kt++) {
        if (kt == NT - 1) {
            asm volatile("s_waitcnt vmcnt(0)" ::: "memory");
        } else {
            asm volatile("s_waitcnt vmcnt(6)" ::: "memory");
        }
        __builtin_amdgcn_s_barrier();
        if (kt + 2 < NT) STAGE(sb, kt + 2);
        const u16* as = &As[rb * 8192];
        const u16* bs = &Bs[rb * 16384];
        bf16x8 av[2][4], bv[2][4];
#pragma unroll
        for (int kk = 0; kk < 2; kk++) {
            const int q  = (lane >> 4) + kk * 4;
            const int sw = (q ^ (lr & 7)) << 3;
#pragma unroll
            for (int i = 0; i < 4; i++)
                av[kk][i] = *(const bf16x8*)&as[(wm + i * 16 + lr) * 64 + sw];
#pragma unroll
            for (int j = 0; j < 4; j++)
                bv[kk][j] = *(const bf16x8*)&bs[(wn + j * 16 + lr) * 64 + sw];
        }
        __builtin_amdgcn_s_setprio(1);
#pragma unroll
        for (int kk = 0; kk < 2; kk++)
#pragma unroll
            for (int i = 0; i < 4; i++)
#pragma unroll
                for (int j = 0; j < 4; j++)
                    acc[i][j] = __builtin_amdgcn_mfma_f32_16x16x32_bf16(
                        av[kk][i], bv[kk][j], acc[i][j], 0, 0, 0);
        __builtin_amdgcn_s_setprio(0);
        rb = (rb == 2) ? 0 : rb + 1;
        sb = (sb == 2) ? 0 : sb + 1;
    }

    const int r0 = (lane >> 4) * 4;
#pragma unroll
    for (int i = 0; i < 4; i++) {
#pragma unroll
        for (int j = 0; j < 4; j++) {
            const int col = n0 + wn + j * 16 + lr;
#pragma unroll
            for (int r = 0; r < 4; r++) {
                const int row = m0 + wm + i * 16 + r0 + r;
                float v = acc[i][j][r];
                if (EPI == 0) v = mishf(v + bias[row]);
                Db[(size_t)row * N + col] = f2bf(v);
            }
        }
    }
}

__global__ __launch_bounds__(512, 2)
void gemm1_k(const u16* __restrict__ A, const u16* __restrict__ Bt,
             u16* __restrict__ D, const float* __restrict__ bias,
             int N, int Kd)
{
    bgemm_body<0>(A, Bt, D, bias, N, Kd);
}

// M2[b] = w2s[b] (DI x O) . pwb[b]^T (C x O)  -> bf16 [b][DI][C]
__global__ __launch_bounds__(512, 2)
void m2_k(const u16* __restrict__ A, const u16* __restrict__ Bt,
          u16* __restrict__ D)
{
    const int b = blockIdx.z;
    bgemm_body<3>(A + (size_t)b * DI_ * O_, Bt + (size_t)b * C_ * O_,
                  D + (size_t)b * DI_ * C_, nullptr, C_, O_);
}

// ===== final GEMM: 2-wave 64x128 tile, BK=32, 3-buf counted vmcnt ===========
// out[bt][i] = y1gT[bt,:].M2[b][i,:] + w2b[i] + pb2[b][i] + x[bt][i]  (f32)
__global__ __launch_bounds__(128, 2)
void fgemm_k(const u16* __restrict__ A, const u16* __restrict__ Bt,
             float* __restrict__ Df, const float* __restrict__ bias,
             const float* __restrict__ pb2, const float* __restrict__ X)
{
    __shared__ u16 As[3 * 2048];
    __shared__ u16 Bs[3 * 4096];
    const int N = DI_, Kd = C_;

    const int gx = gridDim.x;
    const unsigned nwg = (unsigned)gx * gridDim.y;
    unsigned lin = blockIdx.y * gx + blockIdx.x;
    lin = (lin & 7u) * (nwg >> 3) + (lin >> 3);
    const int m0 = (int)(lin / gx) * 64;
    const int n0 = (int)(lin % gx) * 128;
    const int b  = m0 >> 10;
    const u16* Bb = Bt + (size_t)b * DI_ * C_;

    const int tid  = threadIdx.x;
    const int lane = tid & 63, wave = tid >> 6;
    const int wn = wave * 64;
    const int lr = lane & 15;
    const int q  = lane >> 4;
    const int srow  = lane >> 2;
    const int scolE = ((lane & 3) ^ ((lane >> 3) & 3)) * 8;
    const int sw    = (q ^ ((lr >> 1) & 3)) << 3;

    f32x4 acc[4][4];
#pragma unroll
    for (int i = 0; i < 4; i++)
#pragma unroll
        for (int j = 0; j < 4; j++) acc[i][j] = (f32x4){0.f, 0.f, 0.f, 0.f};

    auto STAGE = [&](int buf, int kt) {
        const int k0 = kt << 5;
#pragma unroll
        for (int i = 0; i < 2; i++)
            GLOAD_LDS16(&A[(size_t)(m0 + wave * 32 + i * 16 + srow) * Kd + k0 + scolE],
                        &As[buf * 2048 + (wave * 32 + i * 16) * 32]);
#pragma unroll
        for (int i = 0; i < 4; i++)
            GLOAD_LDS16(&Bb[(size_t)(n0 + wave * 64 + i * 16 + srow) * Kd + k0 + scolE],
                        &Bs[buf * 4096 + (wave * 64 + i * 16) * 32]);
    };

    const int NT = Kd >> 5;
    STAGE(0, 0);
    STAGE(1, 1);
    int rb = 0, sb = 2;
    for (int kt = 0; kt < NT; kt++) {
        if (kt == NT - 1) {
            asm volatile("s_waitcnt vmcnt(0)" ::: "memory");
        } else {
            asm volatile("s_waitcnt vmcnt(6)" ::: "memory");
        }
        __builtin_amdgcn_s_barrier();
        if (kt + 2 < NT) STAGE(sb, kt + 2);
        const u16* as = &As[rb * 2048];
        const u16* bs = &Bs[rb * 4096];
        bf16x8 av[4], bv[4];
#pragma unroll
        for (int i = 0; i < 4; i++)
            av[i] = *(const bf16x8*)&as[(i * 16 + lr) * 32 + sw];
#pragma unroll
        for (int j = 0; j < 4; j++)
            bv[j] = *(const bf16x8*)&bs[(wn + j * 16 + lr) * 32 + sw];
        __builtin_amdgcn_s_setprio(1);
#pragma unroll
        for (int i = 0; i < 4; i++)
#pragma unroll
            for (int j = 0; j < 4; j++)
                acc[i][j] = __builtin_amdgcn_mfma_f32_16x16x32_bf16(
                    av[i], bv[j], acc[i][j], 0, 0, 0);
        __builtin_amdgcn_s_setprio(0);
        rb = (rb == 2) ? 0 : rb + 1;
        sb = (sb == 2) ? 0 : sb + 1;
    }

    const int r0 = (lane >> 4) * 4;
#pragma unroll
    for (int i = 0; i < 4; i++) {
#pragma unroll
        for (int j = 0; j < 4; j++) {
            const int col = n0 + wn + j * 16 + lr;
            const float cadd = bias[col] + pb2[b * DI_ + col];
#pragma unroll
            for (int r = 0; r < 4; r++) {
                const int row = m0 + i * 16 + r0 + r;
                Df[(size_t)row * N + col] =
                    acc[i][j][r] + cadd + X[(size_t)row * N + col];
            }
        }
    }
}

extern "C" void kernel_launch(void* const* d_in, const int* in_sizes, int n_in,
                              void* d_out, int out_size, void* d_ws, size_t ws_size,
                              hipStream_t stream)
{
    const float* x   = (const float*)d_in[0];
    const float* d_w = (const float*)d_in[1];
    const float* d_g = (const float*)d_in[2];
    const float* d_b = (const float*)d_in[3];
    const float* p_w = (const float*)d_in[4];
    const float* p_g = (const float*)d_in[5];
    const float* p_b = (const float*)d_in[6];
    const float* w1w = (const float*)d_in[7];
    const float* w1b = (const float*)d_in[8];
    const float* w2w = (const float*)d_in[9];
    const float* w2b = (const float*)d_in[10];
    float* out = (float*)d_out;

    char* ws = (char*)d_ws;
    const size_t SZ = (size_t)16777216;           // 16 MB
    u16*   h    = (u16*)(ws);                     // [C][B*T] bf16
    u16*   y1gT = (u16*)(ws + SZ);                // [B*T][C] bf16
    u16*   pwb  = (u16*)(ws + 2 * SZ);            // [B][C][O] bf16 (p_w * g)
    u16*   xb   = (u16*)(ws + 3 * SZ);            // [B*T][DI] bf16 (4 MB)
    u16*   w1b16= (u16*)(ws + 3 * SZ + 4194304);  // [C][DI] bf16 (0.5 MB)
    u16*   w2s  = (u16*)(ws + 3 * SZ + 4718592);  // [B][DI][O] bf16 (4 MB)
    u16*   M2   = (u16*)(ws + 3 * SZ + 8912896);  // [B][DI][C] bf16 (4 MB)
    float* dwf  = (float*)(ws + 3 * SZ + 13107200);  // B*C*KW f32
    float* part = (float*)(ws + 3 * SZ + 13402112);  // B*16*O f32
    float* pb2  = (float*)(ws + 3 * SZ + 13926400);  // B*DI f32

    prep_k<<<dim3(PB_TOT), 256, 0, stream>>>(
        x, xb, w1w, w1b16, d_w, d_g, dwf, p_w, p_g, pwb, part, w2w, p_b, pb2);

    w2s_k<<<dim3(128), 256, 0, stream>>>(w2w, part, w2s);

    // GEMM1: h[c][bt] = mish(w1[c,:] . xb[bt,:] + w1b[c]);  M=C, N=B*T, K=DI
    gemm1_k<<<dim3(BT_ / 256, C_ / 128), 512, 0, stream>>>(
        w1b16, xb, h, w1b, BT_, DI_);

    dwconv_k<<<dim3(T_ / 64, C_ / 64, B_), 256, 0, stream>>>(h, dwf, d_b, y1gT);

    // M2[b] = w2s[b] . pwb[b]^T ;  M=DI, N=C, K=O per batch
    m2_k<<<dim3(C_ / 256, DI_ / 128, B_), 512, 0, stream>>>(w2s, pwb, M2);

    // out[bt][i] = y1gT[bt,:] . M2[b][i,:] + w2b[i] + pb2[b][i] + x[bt][i]
    fgemm_k<<<dim3(DI_ / 128, BT_ / 64), 128, 0, stream>>>(
        y1gT, M2, out, w2b, pb2, x);
}

// Round 13
// 104.933 us; speedup vs baseline: 1.2417x; 1.2417x over previous
//
#include <hip/hip_runtime.h>
#include <hip/hip_bf16.h>

#define B_  8
#define T_  1024
#define DI_ 256
#define C_  1024
#define O_  1024
#define KW  9
#define BT_ 8192
#define EPSF 1e-12f

typedef unsigned short u16;
typedef u16   ushort8 __attribute__((ext_vector_type(8)));
typedef u16   ushort4v __attribute__((ext_vector_type(4)));
typedef __bf16 bf16x8 __attribute__((ext_vector_type(8)));
typedef float  f32x4  __attribute__((ext_vector_type(4)));

#define GLOAD_LDS16(g, l) __builtin_amdgcn_global_load_lds( \
    (const __attribute__((address_space(1))) void*)(g),      \
    (__attribute__((address_space(3))) void*)(l), 16, 0, 0)

__device__ __forceinline__ float bf2f(u16 u) {
    union { unsigned int i; float f; } z; z.i = ((unsigned int)u) << 16; return z.f;
}
__device__ __forceinline__ u16 f2bf(float f) {
    union { float f; unsigned int i; } z; z.f = f;
    unsigned int i = z.i;
    i += 0x7FFFu + ((i >> 16) & 1u);   // RNE
    return (u16)(i >> 16);
}
__device__ __forceinline__ float mishf(float v) {
    float u = __expf(v);
    float w = 1.f + u;
    return v * (1.f - 2.f / (w * w + 1.f));
}

// ================= mega prep kernel =========================================
// [0,2048) cvt xb | [2048,2304) cvt w1 | [2304,2312) dnorm
// [2312,2440) pw streaming: ssq partials + pwb=bf16(p_w*g), float4 rows
// [2440,2504) pb2[b][i] = sum_o w2[i][o]*p_b[b][o], one dot per wave-iter
#define PB_XB 2048
#define PB_W1 2304
#define PB_DN 2312
#define PB_PW 2440
#define PB_TOT 2504

__global__ __launch_bounds__(256)
void prep_k(const float* __restrict__ x,   u16* __restrict__ xb,
            const float* __restrict__ w1w, u16* __restrict__ w1b16,
            const float* __restrict__ d_w, const float* __restrict__ d_g,
            float* __restrict__ dwf,
            const float* __restrict__ p_w, const float* __restrict__ p_g,
            u16* __restrict__ pwb, float* __restrict__ part,
            const float* __restrict__ w2w, const float* __restrict__ p_b,
            float* __restrict__ pb2)
{
    const int bid = blockIdx.x;
    const int tid = threadIdx.x;

    if (bid < PB_W1) {
        const float* in;
        u16* out;
        int i;
        if (bid < PB_XB) { in = x;   out = xb;    i = bid * 256 + tid; }
        else             { in = w1w; out = w1b16; i = (bid - PB_XB) * 256 + tid; }
        float4 v = ((const float4*)in)[i];
        ushort4v o;
        o.x = f2bf(v.x); o.y = f2bf(v.y); o.z = f2bf(v.z); o.w = f2bf(v.w);
        ((ushort4v*)out)[i] = o;
    } else if (bid < PB_DN) {
        // ---- depthwise weight norm ----
        __shared__ float red[KW][256];
        __shared__ float nrm[KW];
        const int b = bid - PB_W1;
        float s[KW];
#pragma unroll
        for (int k = 0; k < KW; k++) s[k] = 0.f;
        for (int c = tid; c < C_; c += 256) {
#pragma unroll
            for (int k = 0; k < KW; k++) {
                float v = d_w[((size_t)b * C_ + c) * KW + k];
                s[k] += v * v;
            }
        }
#pragma unroll
        for (int k = 0; k < KW; k++) red[k][tid] = s[k];
        __syncthreads();
        if (tid < KW) {
            float t = 0.f;
            for (int i = 0; i < 256; i++) t += red[tid][i];
            nrm[tid] = fmaxf(sqrtf(t), EPSF);
        }
        __syncthreads();
        for (int c = tid; c < C_; c += 256) {
            float g = d_g[(size_t)b * C_ + c];
#pragma unroll
            for (int k = 0; k < KW; k++)
                dwf[((size_t)b * C_ + c) * KW + k] =
                    d_w[((size_t)b * C_ + c) * KW + k] / nrm[k] * g;
        }
    } else if (bid < PB_PW) {
        // ---- pw streaming: 128 blocks = b*16 + cch(64 rows each) ----
        const int idx = bid - PB_DN;
        const int b = idx >> 4, cch = idx & 15;
        const int o = tid * 4;
        const float* src = p_w + ((size_t)b * C_ + cch * 64) * O_ + o;
        const float* gp  = p_g + (size_t)b * C_ + cch * 64;
        u16* dst = pwb + ((size_t)b * C_ + cch * 64) * O_ + o;
        float4 ssq = {0.f, 0.f, 0.f, 0.f};
#pragma unroll 4
        for (int r = 0; r < 64; r++) {
            float4 v = *(const float4*)(src + (size_t)r * O_);
            float g = gp[r];
            ssq.x += v.x * v.x; ssq.y += v.y * v.y;
            ssq.z += v.z * v.z; ssq.w += v.w * v.w;
            ushort4v ov;
            ov.x = f2bf(v.x * g); ov.y = f2bf(v.y * g);
            ov.z = f2bf(v.z * g); ov.w = f2bf(v.w * g);
            *(ushort4v*)(dst + (size_t)r * O_) = ov;
        }
        *(float4*)&part[((size_t)b * 16 + cch) * O_ + o] = ssq;
    } else {
        // ---- pb2: 64 blocks = b*8 + ich(32 i's); one dot per wave-iter ----
        const int idx = bid - PB_PW;
        const int b = idx >> 3, ich = idx & 7;
        const int wave = tid >> 6, lane = tid & 63;
        float4 pb[4];
#pragma unroll
        for (int q = 0; q < 4; q++)
            pb[q] = *(const float4*)&p_b[(size_t)b * O_ + q * 256 + lane * 4];
        for (int k = 0; k < 8; k++) {
            const int i = ich * 32 + wave * 8 + k;
            float s = 0.f;
#pragma unroll
            for (int q = 0; q < 4; q++) {
                float4 w = *(const float4*)&w2w[(size_t)i * O_ + q * 256 + lane * 4];
                s += w.x * pb[q].x + w.y * pb[q].y + w.z * pb[q].z + w.w * pb[q].w;
            }
#pragma unroll
            for (int m = 1; m < 64; m <<= 1) s += __shfl_xor(s, m, 64);
            if (lane == 0) pb2[b * DI_ + i] = s;
        }
    }
}

// ---------------- depthwise conv along t + transpose write -------------------
__global__ __launch_bounds__(256)
void dwconv_k(const u16* __restrict__ h, const float* __restrict__ dwf,
              const float* __restrict__ d_b, u16* __restrict__ y1gT)
{
    __shared__ u16 hs[64][74];
    const int b  = blockIdx.z;
    const int c0 = blockIdx.y * 64, t0 = blockIdx.x * 64;
    const int tid = threadIdx.x;
    for (int idx = tid; idx < 64 * 72; idx += 256) {
        int cc = idx / 72, tt = idx % 72;
        int t = t0 + tt - 4;
        u16 v = 0;
        if (t >= 0 && t < T_) v = h[(size_t)(c0 + cc) * BT_ + b * T_ + t];
        hs[cc][tt] = v;
    }
    __syncthreads();
    const int cc = tid & 63;
    const int c  = c0 + cc;
    float w[KW];
#pragma unroll
    for (int k = 0; k < KW; k++) w[k] = dwf[((size_t)b * C_ + c) * KW + k];
    const float bb = d_b[(size_t)b * C_ + c];
    for (int tt = tid >> 6; tt < 64; tt += 4) {
        float s = bb;
#pragma unroll
        for (int k = 0; k < KW; k++) s += bf2f(hs[cc][tt + k]) * w[k];
        y1gT[((size_t)b * T_ + t0 + tt) * C_ + c] = f2bf(s);
    }
}

// ===== big GEMM body: 512 thr, BM=128 x BN=256, BK=64, 3-buf counted vmcnt ==
// EPI 0: D(bf16) = mish(v + bias[row]);  EPI 3: D(bf16) = v (no bias)
template<int EPI>
__device__ __forceinline__ void bgemm_body(
    const u16* __restrict__ A, const u16* __restrict__ Bt,
    u16* __restrict__ Db, const float* __restrict__ bias,
    int m0, int n0, int N, int Kd)
{
    __shared__ u16 As[3 * 128 * 64];   // 48 KB
    __shared__ u16 Bs[3 * 256 * 64];   // 96 KB

    const int tid  = threadIdx.x;
    const int lane = tid & 63, wave = tid >> 6;
    const int wm = (wave >> 2) * 64, wn = (wave & 3) * 64;
    const int lr = lane & 15;
    const int srow8 = tid >> 3;
    const int scolE = ((tid & 7) ^ ((tid >> 3) & 7)) * 8;

    f32x4 acc[4][4];
#pragma unroll
    for (int i = 0; i < 4; i++)
#pragma unroll
        for (int j = 0; j < 4; j++) acc[i][j] = (f32x4){0.f, 0.f, 0.f, 0.f};

    auto STAGE = [&](int buf, int kt) {
        const int k0 = kt << 6;
#pragma unroll
        for (int i = 0; i < 2; i++)
            GLOAD_LDS16(&A[(size_t)(m0 + i * 64 + srow8) * Kd + k0 + scolE],
                        &As[buf * 8192 + (i * 64 + wave * 8) * 64]);
#pragma unroll
        for (int i = 0; i < 4; i++)
            GLOAD_LDS16(&Bt[(size_t)(n0 + i * 64 + srow8) * Kd + k0 + scolE],
                        &Bs[buf * 16384 + (i * 64 + wave * 8) * 64]);
    };

    const int NT = Kd >> 6;
    STAGE(0, 0);
    STAGE(1, 1);
    int rb = 0, sb = 2;
    for (int kt = 0; kt < NT; kt++) {
        if (kt == NT - 1) {
            asm volatile("s_waitcnt vmcnt(0)" ::: "memory");
        } else {
            asm volatile("s_waitcnt vmcnt(6)" ::: "memory");
        }
        __builtin_amdgcn_s_barrier();
        if (kt + 2 < NT) STAGE(sb, kt + 2);
        const u16* as = &As[rb * 8192];
        const u16* bs = &Bs[rb * 16384];
        bf16x8 av[2][4], bv[2][4];
#pragma unroll
        for (int kk = 0; kk < 2; kk++) {
            const int q  = (lane >> 4) + kk * 4;
            const int sw = (q ^ (lr & 7)) << 3;
#pragma unroll
            for (int i = 0; i < 4; i++)
                av[kk][i] = *(const bf16x8*)&as[(wm + i * 16 + lr) * 64 + sw];
#pragma unroll
            for (int j = 0; j < 4; j++)
                bv[kk][j] = *(const bf16x8*)&bs[(wn + j * 16 + lr) * 64 + sw];
        }
        __builtin_amdgcn_s_setprio(1);
#pragma unroll
        for (int kk = 0; kk < 2; kk++)
#pragma unroll
            for (int i = 0; i < 4; i++)
#pragma unroll
                for (int j = 0; j < 4; j++)
                    acc[i][j] = __builtin_amdgcn_mfma_f32_16x16x32_bf16(
                        av[kk][i], bv[kk][j], acc[i][j], 0, 0, 0);
        __builtin_amdgcn_s_setprio(0);
        rb = (rb == 2) ? 0 : rb + 1;
        sb = (sb == 2) ? 0 : sb + 1;
    }

    const int r0 = (lane >> 4) * 4;
#pragma unroll
    for (int i = 0; i < 4; i++) {
#pragma unroll
        for (int j = 0; j < 4; j++) {
            const int col = n0 + wn + j * 16 + lr;
#pragma unroll
            for (int r = 0; r < 4; r++) {
                const int row = m0 + wm + i * 16 + r0 + r;
                float v = acc[i][j][r];
                if (EPI == 0) v = mishf(v + bias[row]);
                Db[(size_t)row * N + col] = f2bf(v);
            }
        }
    }
}

// ===== merged launch: [0,256) gemm1 tiles | [256,384) w2s blocks ============
__global__ __launch_bounds__(512, 2)
void g1w2_k(const u16* __restrict__ A, const u16* __restrict__ Bt,
            u16* __restrict__ D, const float* __restrict__ bias,
            const float* __restrict__ w2w, const float* __restrict__ part,
            u16* __restrict__ w2s)
{
    const int bid = blockIdx.x;
    if (bid < 256) {
        // gemm1: M=C (8 m-tiles of 128), N=BT (32 n-tiles of 256), K=DI
        const unsigned swz = (bid & 7u) * 32 + (bid >> 3);
        const int m0 = (int)(swz / 32) * 128;
        const int n0 = (int)(swz % 32) * 256;
        bgemm_body<0>(A, Bt, D, bias, m0, n0, BT_, DI_);
    } else {
        // w2s[b][i][o] = bf16(w2[i][o] * inv_np[b][o]), float4-streamed
        const int wid = bid - 256;          // 0..127
        const int b = wid >> 4, ich = wid & 15;
        const int tid = threadIdx.x;
        const int o = (tid & 255) * 4;
        const int rr = tid >> 8;            // 0..1
        float4 s4 = {0.f, 0.f, 0.f, 0.f};
#pragma unroll
        for (int ch = 0; ch < 16; ch++) {
            float4 p = *(const float4*)&part[((size_t)b * 16 + ch) * O_ + o];
            s4.x += p.x; s4.y += p.y; s4.z += p.z; s4.w += p.w;
        }
        float4 inv4;
        inv4.x = 1.f / fmaxf(sqrtf(s4.x), EPSF);
        inv4.y = 1.f / fmaxf(sqrtf(s4.y), EPSF);
        inv4.z = 1.f / fmaxf(sqrtf(s4.z), EPSF);
        inv4.w = 1.f / fmaxf(sqrtf(s4.w), EPSF);
        for (int r = rr; r < 16; r += 2) {
            const int i = ich * 16 + r;
            float4 w = *(const float4*)&w2w[(size_t)i * O_ + o];
            ushort4v ov;
            ov.x = f2bf(w.x * inv4.x); ov.y = f2bf(w.y * inv4.y);
            ov.z = f2bf(w.z * inv4.z); ov.w = f2bf(w.w * inv4.w);
            *(ushort4v*)&w2s[((size_t)b * DI_ + i) * O_ + o] = ov;
        }
    }
}

// M2[b] = w2s[b] (DI x O) . pwb[b]^T (C x O) -> bf16 [b][DI][C]; 64 blocks
__global__ __launch_bounds__(512, 2)
void m2_k(const u16* __restrict__ w2s, const u16* __restrict__ pwb,
          u16* __restrict__ M2)
{
    const int bid = blockIdx.x;          // b*8 + r
    const int b = bid >> 3, r = bid & 7;
    const int m0 = (r & 1) * 128;
    const int n0 = (r >> 1) * 256;
    bgemm_body<3>(w2s + (size_t)b * DI_ * O_, pwb + (size_t)b * C_ * O_,
                  M2 + (size_t)b * DI_ * C_, nullptr, m0, n0, C_, O_);
}

// ===== final GEMM: 2-wave 64x128 tile, BK=32, 3-buf counted vmcnt ===========
// out[bt][i] = y1gT[bt,:].M2[b][i,:] + w2b[i] + pb2[b][i] + x[bt][i]  (f32)
__global__ __launch_bounds__(128, 2)
void fgemm_k(const u16* __restrict__ A, const u16* __restrict__ Bt,
             float* __restrict__ Df, const float* __restrict__ bias,
             const float* __restrict__ pb2, const float* __restrict__ X)
{
    __shared__ u16 As[3 * 2048];
    __shared__ u16 Bs[3 * 4096];
    const int N = DI_, Kd = C_;

    const int gx = gridDim.x;
    const unsigned nwg = (unsigned)gx * gridDim.y;
    unsigned lin = blockIdx.y * gx + blockIdx.x;
    lin = (lin & 7u) * (nwg >> 3) + (lin >> 3);
    const int m0 = (int)(lin / gx) * 64;
    const int n0 = (int)(lin % gx) * 128;
    const int b  = m0 >> 10;
    const u16* Bb = Bt + (size_t)b * DI_ * C_;

    const int tid  = threadIdx.x;
    const int lane = tid & 63, wave = tid >> 6;
    const int wn = wave * 64;
    const int lr = lane & 15;
    const int q  = lane >> 4;
    const int srow  = lane >> 2;
    const int scolE = ((lane & 3) ^ ((lane >> 3) & 3)) * 8;
    const int sw    = (q ^ ((lr >> 1) & 3)) << 3;

    f32x4 acc[4][4];
#pragma unroll
    for (int i = 0; i < 4; i++)
#pragma unroll
        for (int j = 0; j < 4; j++) acc[i][j] = (f32x4){0.f, 0.f, 0.f, 0.f};

    auto STAGE = [&](int buf, int kt) {
        const int k0 = kt << 5;
#pragma unroll
        for (int i = 0; i < 2; i++)
            GLOAD_LDS16(&A[(size_t)(m0 + wave * 32 + i * 16 + srow) * Kd + k0 + scolE],
                        &As[buf * 2048 + (wave * 32 + i * 16) * 32]);
#pragma unroll
        for (int i = 0; i < 4; i++)
            GLOAD_LDS16(&Bb[(size_t)(n0 + wave * 64 + i * 16 + srow) * Kd + k0 + scolE],
                        &Bs[buf * 4096 + (wave * 64 + i * 16) * 32]);
    };

    const int NT = Kd >> 5;
    STAGE(0, 0);
    STAGE(1, 1);
    int rb = 0, sb = 2;
    for (int kt = 0; kt < NT; kt++) {
        if (kt == NT - 1) {
            asm volatile("s_waitcnt vmcnt(0)" ::: "memory");
        } else {
            asm volatile("s_waitcnt vmcnt(6)" ::: "memory");
        }
        __builtin_amdgcn_s_barrier();
        if (kt + 2 < NT) STAGE(sb, kt + 2);
        const u16* as = &As[rb * 2048];
        const u16* bs = &Bs[rb * 4096];
        bf16x8 av[4], bv[4];
#pragma unroll
        for (int i = 0; i < 4; i++)
            av[i] = *(const bf16x8*)&as[(i * 16 + lr) * 32 + sw];
#pragma unroll
        for (int j = 0; j < 4; j++)
            bv[j] = *(const bf16x8*)&bs[(wn + j * 16 + lr) * 32 + sw];
        __builtin_amdgcn_s_setprio(1);
#pragma unroll
        for (int i = 0; i < 4; i++)
#pragma unroll
            for (int j = 0; j < 4; j++)
                acc[i][j] = __builtin_amdgcn_mfma_f32_16x16x32_bf16(
                    av[i], bv[j], acc[i][j], 0, 0, 0);
        __builtin_amdgcn_s_setprio(0);
        rb = (rb == 2) ? 0 : rb + 1;
        sb = (sb == 2) ? 0 : sb + 1;
    }

    const int r0 = (lane >> 4) * 4;
#pragma unroll
    for (int i = 0; i < 4; i++) {
#pragma unroll
        for (int j = 0; j < 4; j++) {
            const int col = n0 + wn + j * 16 + lr;
            const float cadd = bias[col] + pb2[b * DI_ + col];
#pragma unroll
            for (int r = 0; r < 4; r++) {
                const int row = m0 + i * 16 + r0 + r;
                Df[(size_t)row * N + col] =
                    acc[i][j][r] + cadd + X[(size_t)row * N + col];
            }
        }
    }
}

extern "C" void kernel_launch(void* const* d_in, const int* in_sizes, int n_in,
                              void* d_out, int out_size, void* d_ws, size_t ws_size,
                              hipStream_t stream)
{
    const float* x   = (const float*)d_in[0];
    const float* d_w = (const float*)d_in[1];
    const float* d_g = (const float*)d_in[2];
    const float* d_b = (const float*)d_in[3];
    const float* p_w = (const float*)d_in[4];
    const float* p_g = (const float*)d_in[5];
    const float* p_b = (const float*)d_in[6];
    const float* w1w = (const float*)d_in[7];
    const float* w1b = (const float*)d_in[8];
    const float* w2w = (const float*)d_in[9];
    const float* w2b = (const float*)d_in[10];
    float* out = (float*)d_out;

    char* ws = (char*)d_ws;
    const size_t SZ = (size_t)16777216;           // 16 MB
    u16*   h    = (u16*)(ws);                     // [C][B*T] bf16
    u16*   y1gT = (u16*)(ws + SZ);                // [B*T][C] bf16
    u16*   pwb  = (u16*)(ws + 2 * SZ);            // [B][C][O] bf16 (p_w * g)
    u16*   xb   = (u16*)(ws + 3 * SZ);            // [B*T][DI] bf16 (4 MB)
    u16*   w1b16= (u16*)(ws + 3 * SZ + 4194304);  // [C][DI] bf16 (0.5 MB)
    u16*   w2s  = (u16*)(ws + 3 * SZ + 4718592);  // [B][DI][O] bf16 (4 MB)
    u16*   M2   = (u16*)(ws + 3 * SZ + 8912896);  // [B][DI][C] bf16 (4 MB)
    float* dwf  = (float*)(ws + 3 * SZ + 13107200);  // B*C*KW f32
    float* part = (float*)(ws + 3 * SZ + 13402112);  // B*16*O f32
    float* pb2  = (float*)(ws + 3 * SZ + 13926400);  // B*DI f32

    prep_k<<<dim3(PB_TOT), 256, 0, stream>>>(
        x, xb, w1w, w1b16, d_w, d_g, dwf, p_w, p_g, pwb, part, w2w, p_b, pb2);

    // gemm1 (h = mish(w1.xb)) + w2s (w2 * inv_np) in one launch
    g1w2_k<<<dim3(384), 512, 0, stream>>>(
        w1b16, xb, h, w1b, w2w, part, w2s);

    dwconv_k<<<dim3(T_ / 64, C_ / 64, B_), 256, 0, stream>>>(h, dwf, d_b, y1gT);

    // M2[b] = w2s[b] . pwb[b]^T ;  M=DI, N=C, K=O per batch
    m2_k<<<dim3(64), 512, 0, stream>>>(w2s, pwb, M2);

    // out[bt][i] = y1gT[bt,:] . M2[b][i,:] + w2b[i] + pb2[b][i] + x[bt][i]
    fgemm_k<<<dim3(DI_ / 128, BT_ / 64), 128, 0, stream>>>(
        y1gT, M2, out, w2b, pb2, x);
}